// Round 2
// baseline (452.451 us; speedup 1.0000x reference)
//
#include <hip/hip_runtime.h>
#include <hip/hip_bf16.h>
#include <stdint.h>

#define AS1 __attribute__((address_space(1)))
#define AS3 __attribute__((address_space(3)))

typedef __attribute__((ext_vector_type(8))) short bf16x8;
typedef __attribute__((ext_vector_type(4))) short short4v;
typedef __attribute__((ext_vector_type(4))) float f32x4;

static constexpr int D = 128;
static constexpr int M = 131072;
static constexpr int KHALF = 65536;   // M/2
static constexpr int FIVE_D = 640;
static constexpr int FLAGBIT = 1 << 30;
static constexpr int IDXMASK = FLAGBIT - 1;

// async 16B global->LDS (m97: global_load_lds_dwordx4); lds base wave-uniform + lane*16
__device__ __forceinline__ void gl_lds16(const void* g, void* l) {
  __builtin_amdgcn_global_load_lds((const AS1 void*)g, (AS3 void*)l, 16, 0, 0);
}

__device__ __forceinline__ short f2bf(float x) {
  __hip_bfloat16 h = __float2bfloat16(x);
  return (short)__bfloat16_as_ushort(h);
}

// Invert the scatter: tab[to] = from | (pool<<30). Left uses (bot0, prev0), right (bot1, prev1).
__global__ void build_tables(const int* __restrict__ bf0, const int* __restrict__ bt0,
                             const int* __restrict__ pf0, const int* __restrict__ pt0,
                             const int* __restrict__ bf1, const int* __restrict__ bt1,
                             const int* __restrict__ pf1, const int* __restrict__ pt1,
                             int* __restrict__ tabL, int* __restrict__ tabR) {
  int j = blockIdx.x * blockDim.x + threadIdx.x;
  if (j < KHALF) {
    tabL[bt0[j]] = bf0[j];
    tabL[pt0[j]] = pf0[j] | FLAGBIT;
    tabR[bt1[j]] = bf1[j];
    tabR[pt1[j]] = pf1[j] | FLAGBIT;
  }
}

// Pack + convert W [256,640] f32 row-major -> bf16 Wp[c][n][kk] (c = k-chunk of 32):
// main-loop staging becomes a linear 16B-wide copy, B-fragments contiguous 16B in LDS.
__global__ void pack_w(const float* __restrict__ W, unsigned short* __restrict__ P) {
  int idx = blockIdx.x * blockDim.x + threadIdx.x;  // < 8*640*32 = 163840
  int c = idx / (FIVE_D * 32);
  int rem = idx - c * (FIVE_D * 32);
  int n = rem >> 5;
  int kk = rem & 31;
  P[idx] = __bfloat16_as_ushort(__float2bfloat16(W[(c * 32 + kk) * FIVE_D + n]));
}

__global__ __launch_bounds__(512, 4) void tree_lstm_fused(
    const float* __restrict__ h_bot, const float* __restrict__ c_bot,
    const float* __restrict__ h_buf, const float* __restrict__ c_buf,
    const unsigned short* __restrict__ Wp, const float* __restrict__ bias,
    const int* __restrict__ tabL, const int* __restrict__ tabR,
    float* __restrict__ out) {
  // LDS: A tile 64 rows x 32 k bf16 (4KB) + W chunk 640 cols x 32 k bf16 (40KB) = 44KB
  __shared__ __align__(16) short A_lds[64 * 32];
  __shared__ __align__(16) short W_lds[FIVE_D * 32];

  const int tid = threadIdx.x;
  const int lane = tid & 63;
  const int wv = tid >> 6;      // wave id 0..7 = in-gate 16-col chunk
  const int quad = lane >> 4;   // 0..3
  const int l16 = lane & 15;
  const int m_base = blockIdx.x * 64;

  f32x4 acc[4][5];              // 4 M-subtiles x 5 gates, 16x16 each -> 80 VGPRs
  const f32x4 zero = {0.f, 0.f, 0.f, 0.f};
#pragma unroll
  for (int mt = 0; mt < 4; ++mt)
#pragma unroll
    for (int g = 0; g < 5; ++g) acc[mt][g] = zero;

  // A gather setup: thread t stages row (t>>3), 4-float segment (t&7) of each 32-k chunk
  const int a_row = tid >> 3;
  const int a_seg = tid & 7;
  const int mA = m_base + a_row;
  const int sLa = tabL[mA];
  const int sRa = tabR[mA];
  const float* pL = ((sLa & FLAGBIT) ? h_buf : h_bot) + (size_t)(sLa & IDXMASK) * D + a_seg * 4;
  const float* pR = ((sRa & FLAGBIT) ? h_buf : h_bot) + (size_t)(sRa & IDXMASK) * D + a_seg * 4;

#pragma unroll 1
  for (int c = 0; c < 8; ++c) {
    if (c) __syncthreads();  // protect LDS from overwrite while previous chunk still read
    // W chunk: 40960B = 512 thr * 5 * 16B, linear async copy from packed bf16 Wp
    const unsigned short* wsrc = Wp + c * (FIVE_D * 32);
#pragma unroll
    for (int i = 0; i < 5; ++i) {
      const int off = (i * 512 + tid) * 8;  // shorts; wave base + lane*16B
      gl_lds16(wsrc + off, &W_lds[off]);
    }
    // A chunk: k in [32c,32c+32): h_l for c<4, h_r for c>=4. f32 gather -> cvt -> LDS bf16
    const float* asrc = (c < 4) ? (pL + c * 32) : (pR + (c - 4) * 32);
    const float4 av = *(const float4*)asrc;  // 16B aligned (row base 512B-aligned)
    short4v bv;
    bv.x = f2bf(av.x);
    bv.y = f2bf(av.y);
    bv.z = f2bf(av.z);
    bv.w = f2bf(av.w);
    *(short4v*)&A_lds[tid * 4] = bv;  // 8B ds_write, contiguous by tid, conflict-free
    __syncthreads();  // drains vmcnt (global_load_lds) + lgkmcnt (ds_write)

    bf16x8 afrag[4];
#pragma unroll
    for (int mt = 0; mt < 4; ++mt)
      afrag[mt] = *(const bf16x8*)&A_lds[(mt * 16 + l16) * 32 + 8 * quad];
#pragma unroll
    for (int g = 0; g < 5; ++g) {
      const bf16x8 bfrag = *(const bf16x8*)&W_lds[(g * 128 + wv * 16 + l16) * 32 + 8 * quad];
#pragma unroll
      for (int mt = 0; mt < 4; ++mt)
        acc[mt][g] = __builtin_amdgcn_mfma_f32_16x16x32_bf16(afrag[mt], bfrag, acc[mt][g], 0, 0, 0);
    }
  }

  // Epilogue: wave wv holds gates i,o,u,fl,fr for rows m_base+mt*16+quad*4+r at
  // in-gate col d = wv*16 + l16. C/D layout: col=lane&15, row=quad*4+reg (m89/m91).
  const int d = wv * 16 + l16;
  const float bi = bias[0 * D + d];
  const float bo = bias[1 * D + d];
  const float bu = bias[2 * D + d];
  const float bl = bias[3 * D + d];
  const float br = bias[4 * D + d];
  float* outh = out;
  float* outc = out + (size_t)M * D;

#pragma unroll
  for (int mt = 0; mt < 4; ++mt) {
#pragma unroll
    for (int r = 0; r < 4; ++r) {
      const int m = m_base + mt * 16 + quad * 4 + r;
      const int sL = tabL[m];
      const int sR = tabR[m];
      const float* clp = (sL & FLAGBIT) ? c_buf : c_bot;
      const float* crp = (sR & FLAGBIT) ? c_buf : c_bot;
      const float cl = clp[(size_t)(sL & IDXMASK) * D + d];
      const float cr = crp[(size_t)(sR & IDXMASK) * D + d];
      const float gi = acc[mt][0][r] + bi;
      const float go = acc[mt][1][r] + bo;
      const float gu = acc[mt][2][r] + bu;
      const float gfl = acc[mt][3][r] + bl;
      const float gfr = acc[mt][4][r] + br;
      const float iv = 1.f / (1.f + __expf(-gi));
      const float ov = 1.f / (1.f + __expf(-go));
      const float uv = 2.f / (1.f + __expf(-2.f * gu)) - 1.f;  // tanh, inf-safe
      const float flv = 1.f / (1.f + __expf(-gfl));
      const float frv = 1.f / (1.f + __expf(-gfr));
      const float cc = iv * uv + flv * cl + frv * cr;
      const float hh = ov * (2.f / (1.f + __expf(-2.f * cc)) - 1.f);
      outh[(size_t)m * D + d] = hh;
      outc[(size_t)m * D + d] = cc;
    }
  }
}

extern "C" void kernel_launch(void* const* d_in, const int* in_sizes, int n_in,
                              void* d_out, int out_size, void* d_ws, size_t ws_size,
                              hipStream_t stream) {
  const float* h_bot = (const float*)d_in[0];
  const float* c_bot = (const float*)d_in[1];
  const float* h_buf = (const float*)d_in[2];
  const float* c_buf = (const float*)d_in[3];
  const float* W = (const float*)d_in[4];
  const float* b = (const float*)d_in[5];
  const int* bf0 = (const int*)d_in[6];
  const int* bt0 = (const int*)d_in[7];
  const int* pf0 = (const int*)d_in[8];
  const int* pt0 = (const int*)d_in[9];
  const int* bf1 = (const int*)d_in[10];
  const int* bt1 = (const int*)d_in[11];
  const int* pf1 = (const int*)d_in[12];
  const int* pt1 = (const int*)d_in[13];

  int* tabL = (int*)d_ws;                            // M int32
  int* tabR = tabL + M;                              // M int32
  unsigned short* Wp = (unsigned short*)(tabR + M);  // 163840 bf16

  hipLaunchKernelGGL(build_tables, dim3(KHALF / 256), dim3(256), 0, stream,
                     bf0, bt0, pf0, pt0, bf1, bt1, pf1, pt1, tabL, tabR);
  hipLaunchKernelGGL(pack_w, dim3((8 * FIVE_D * 32) / 256), dim3(256), 0, stream, W, Wp);
  hipLaunchKernelGGL(tree_lstm_fused, dim3(M / 64), dim3(512), 0, stream,
                     h_bot, c_bot, h_buf, c_buf, Wp, b, tabL, tabR, (float*)d_out);
}